// Round 14
// baseline (38.256 us; speedup 1.0000x reference)
//
#include <hip/hip_runtime.h>
#include <math.h>

#define NP   512
#define NT   1024
#define NS   25
#define NPS  (NP*NS)            // 12800
#define MASKN (NP*NT*NS)        // 13107200

// ---- f64 region (double offsets) ----
#define DSA_OFF  0              // dsA [NPS][4]
#define PD_OFF   51200          // pd  [NP][4]
#define NX_OFF   53248
#define NY_OFF   54272
#define NZ_OFF   55296
#define KK_OFF   56320
#define W_OFF    57344          // W64 [NT][10] sign-folded
#define EMPTY_OFF ((size_t)67584 * 8)      // u32[512]
// ---- f32 shadow region (float offsets from F32 base) ----
#define F32_BYTE_OFF (EMPTY_OFF + 2048)
#define FD_OFF   0              // d32  [NPS][4]
#define FPD_OFF  51200          // pd32 [NP][4]
#define FNX_OFF  53248
#define FNY_OFF  54272
#define FNZ_OFF  55296
#define FKK_OFF  56320
#define FW_OFF   57344          // W32 [NT][12], rows prescaled to sum|w|=1

#define CEPS 7.6293945e-06f     // 64 * 2^-23

__device__ __forceinline__ double sgn(double x) {
    return (x > 0.0) ? 1.0 : ((x < 0.0) ? -1.0 : 0.0);
}

// Fused prep: blocks 0..49 rays, 50..53 triangle tables, 54 scatter+emptyMask.
__global__ void prep_all(const float* __restrict__ p,
                         const float* __restrict__ l,
                         const float* __restrict__ hemi,
                         const float* __restrict__ V,
                         const int* __restrict__ indices,
                         const int* __restrict__ pointindex,
                         const float* __restrict__ COL,
                         const float* __restrict__ OPA,
                         double* __restrict__ ws,
                         unsigned* __restrict__ emptyMask,
                         float* __restrict__ out) {
    const int b = blockIdx.x, t = threadIdx.x;
    float* __restrict__ f32w = (float*)((char*)ws + F32_BYTE_OFF);
    if (b < 50) {
        int idx = b * 256 + t;                 // < 12800 exactly
        int pi = idx / NS, si = idx % NS;
        double px = p[pi*3+0], py = p[pi*3+1], pz = p[pi*3+2];
        double lx = l[0], ly = l[1], lz = l[2];
        double ux = lx - px, uy = ly - py, uz = lz - pz;
        double nrm = sqrt(ux*ux + uy*uy + uz*uz);
        ux /= nrm; uy /= nrm; uz /= nrm;
        double c = -uy;
        double wx = -uz, wz = ux;              // w = cross((0,-1,0), u_hat), wy=0
        double m01 = -wz, m10 = wz, m12 = -wx, m21 = wx;
        double q00 = m01*m10;
        double q02 = m01*m12;
        double q11 = m10*m01 + m12*m21;
        double q20 = m21*m10;
        double q22 = m21*m12;
        double ic = 1.0 + c;
        double r00 = 1.0 + q00/ic, r01 = m01,            r02 = q02/ic;
        double r10 = m10,          r11 = 1.0 + q11/ic,   r12 = m12;
        double r20 = q20/ic,       r21 = m21,            r22 = 1.0 + q22/ic;
        double hx = hemi[si*3+0], hy = hemi[si*3+1], hz = hemi[si*3+2];
        double dx = r00*hx + r01*hy + r02*hz + lx - px;
        double dy = r10*hx + r11*hy + r12*hz + ly - py;
        double dz = r20*hx + r21*hy + r22*hz + lz - pz;
        double* dsA = ws + DSA_OFF;
        dsA[idx*4+0] = dx;
        dsA[idx*4+1] = dy;
        dsA[idx*4+2] = dz;
        dsA[idx*4+3] = 0.0;
        *(float4*)(f32w + FD_OFF + idx*4) =
            make_float4((float)dx, (float)dy, (float)dz, 0.0f);
    } else if (b < 54) {
        int n = (b - 50) * 256 + t;            // < 1024 exactly
        const float* v = V + n*12;
        double a0=v[0], a1=v[1], a2=v[2];
        double b0=v[3], b1=v[4], b2=v[5];
        double c0=v[6], c1=v[7], c2=v[8];
        double v3x=v[9], v3y=v[10], v3z=v[11];
        double e1x=b0-a0, e1y=b1-a1, e1z=b2-a2;
        double e2x=c0-a0, e2y=c1-a1, e2z=c2-a2;
        double cx = e1y*e2z - e1z*e2y;
        double cy = e1z*e2x - e1x*e2z;
        double cz = e1x*e2y - e1y*e2x;
        double nn = sqrt(cx*cx + cy*cy + cz*cz);
        double nx = cx/nn, ny = cy/nn, nz = cz/nn;
        double kk = -(nx*v3x + ny*v3y + nz*v3z);
        double Bv = a0*b2 - a2*b0;
        double Dv = a0*b1 - a1*b0;
        double Ec = a0*c2 - a2*c0;
        double G2 = a1*c0 - a0*c1;
        double Fc = Bv*G2;
        double gd = Dv*(Ec*Dv + Fc);
        double gq = Dv*gd;
        double dq = Dv*c0;
        double aq = a0*gq;
        double WGr0 = a1*Bv - a2*Dv, WGr1 = -(a0*Bv), WGr2 = a0*Dv;
        double dg = Dv*G2;
        double WBr0 = -(a1*gd) + dg*WGr0;
        double WBr1 =  a0*gd  + dg*WGr1;
        double WBr2 =            dg*WGr2;
        double dd = Dv*dq;
        double WAr0 = gq - b0*WBr0 - dd*WGr0;
        double WAr1 =    - b0*WBr1 - dd*WGr1;
        double WAr2 =    - b0*WBr2 - dd*WGr2;
        double sg = sgn(Dv*gd), sb = sgn(gq), sa = sgn(aq);
        ws[NX_OFF + n] = nx;
        ws[NY_OFF + n] = ny;
        ws[NZ_OFF + n] = nz;
        ws[KK_OFF + n] = kk;
        double g0 = WGr0*sg, g1 = WGr1*sg, g2 = WGr2*sg;
        double bb0 = WBr0*sb, bb1 = WBr1*sb, bb2 = WBr2*sb;
        double aa0 = WAr0*sa, aa1 = WAr1*sa, aa2 = WAr2*sa;
        double* W = ws + W_OFF + n*10;
        W[0]=g0; W[1]=g1; W[2]=g2;
        W[3]=bb0; W[4]=bb1; W[5]=bb2;
        W[6]=aa0; W[7]=aa1; W[8]=aa2;
        W[9]=0.0;
        f32w[FNX_OFF+n]=(float)nx; f32w[FNY_OFF+n]=(float)ny;
        f32w[FNZ_OFF+n]=(float)nz; f32w[FKK_OFF+n]=(float)kk;
        double wsg = fabs(g0)+fabs(g1)+fabs(g2);
        double wsb = fabs(bb0)+fabs(bb1)+fabs(bb2);
        double wsa = fabs(aa0)+fabs(aa1)+fabs(aa2);
        double ig = wsg>0.0 ? 1.0/wsg : 0.0;
        double ib = wsb>0.0 ? 1.0/wsb : 0.0;
        double ia = wsa>0.0 ? 1.0/wsa : 0.0;
        float* fw = f32w + FW_OFF + n*12;
        fw[0]=(float)(g0*ig);  fw[1]=(float)(g1*ig);  fw[2]=(float)(g2*ig);
        fw[3]=(float)(bb0*ib); fw[4]=(float)(bb1*ib); fw[5]=(float)(bb2*ib);
        fw[6]=(float)(aa0*ia); fw[7]=(float)(aa1*ia); fw[8]=(float)(aa2*ia);
        fw[9]=0.0f; fw[10]=0.0f; fw[11]=0.0f;
    } else {
        emptyMask[t] = 0u;
        emptyMask[t + 256] = 0u;
        __syncthreads();
        for (int i = t; i < NP; i += 256) {
            int pidx = pointindex[i];
            int local = pidx & (NP - 1);
            int surf = indices[pidx*2 + 0];
            int mat  = indices[pidx*2 + 1];
            atomicOr(&emptyMask[local], 1u << surf);
            float* colOut = out + MASKN;
            float* opaOut = out + MASKN + 3*NP;
            float* refOut = out + MASKN + 4*NP;
            colOut[i*3+0] = COL[(surf*8+mat)*3+0];
            colOut[i*3+1] = COL[(surf*8+mat)*3+1];
            colOut[i*3+2] = COL[(surf*8+mat)*3+2];
            float o = OPA[surf*8+mat];
            opaOut[i] = fminf(fmaxf(o, 0.0f), 1.0f);
            refOut[i*3+0] = (float)((double)l[0] - (double)p[i*3+0]);
            refOut[i*3+1] = (float)((double)l[1] - (double)p[i*3+1]);
            refOut[i*3+2] = (float)((double)l[2] - (double)p[i*3+2]);
            double* pd = ws + PD_OFF;
            pd[i*4+0] = (double)p[i*3+0];
            pd[i*4+1] = (double)p[i*3+1];
            pd[i*4+2] = (double)p[i*3+2];
            pd[i*4+3] = 0.0;
            *(float4*)(f32w + FPD_OFF + i*4) =
                make_float4(p[i*3+0], p[i*3+1], p[i*3+2], 0.0f);
        }
    }
}

// Exact f64 recheck (sign tests only; empty handled by caller). Rare.
__device__ __noinline__ unsigned recheck64(const double* __restrict__ ws,
        unsigned ps, unsigned pp, unsigned n, unsigned nn, unsigned ss) {
    const double* s = ws + DSA_OFF + ps*4u;
    const double* o = ws + PD_OFF + pp*4u;
    double nx = ws[NX_OFF+n], ny = ws[NY_OFF+n], nz = ws[NZ_OFF+n];
    double kk = ws[KK_OFF+n];
    double vd = fma(s[2], nz, fma(s[1], ny, s[0]*nx));
    double tt = fma(o[2], nz, fma(o[1], ny, fma(o[0], nx, kk)));
    double e1 = fma(1e-4, vd, -tt);
    double e2 = vd + tt;
    const double* d = ws + DSA_OFF + (pp*25u + ss)*4u;
    double R0 = fma(-tt, d[0], vd*o[0]);
    double R1 = fma(-tt, d[1], vd*o[1]);
    double R2 = fma(-tt, d[2], vd*o[2]);
    const double* w = ws + W_OFF + nn*10u;
    double dG = fma(R2, w[2], fma(R1, w[1], R0*w[0]));
    double dB = fma(R2, w[5], fma(R1, w[4], R0*w[3]));
    double dA = fma(R2, w[8], fma(R1, w[7], R0*w[6]));
    int hv = __double2hiint(vd);
    int m = (__double2hiint(e1)^hv) | (__double2hiint(e2)^hv)
          | (__double2hiint(dG)^hv) | (__double2hiint(dB)^hv)
          | (__double2hiint(dA)^hv);
    return (m >= 0) ? 1u : 0u;
}

// Round 14: R7's exact 33.6us structure + 2-deep operand software pipeline.
// Theory: R7 is dependency-latency bound (ds_read ~120cyc, VGPR-starved
// compiler issues loads just-in-time). Double-buffer ONE element's operands
// (13 floats) so element k's compute hides element k+1's LDS reads.
__global__ __launch_bounds__(256) void diffuse_main(
        const double* __restrict__ ws,
        const unsigned* __restrict__ emptyMask,
        float* __restrict__ out) {
    __shared__ float sW[42][12];
    __shared__ float sdx[25], sdy[25], sdz[25], sdm[25];

    const float* __restrict__ f32 = (const float*)((const char*)ws + F32_BYTE_OFF);
    const unsigned ps = blockIdx.x;
    const unsigned pp = ps / 25u;
    const unsigned q  = ps - pp*25u;
    const unsigned nn0 = (q << 10) / 25u;
    const unsigned tid = threadIdx.x;
    const unsigned n0 = tid * 4u;

    // per-thread coalesced table loads (f32), issued before barrier
    const float4 fnx = *(const float4*)(f32 + FNX_OFF + n0);
    const float4 fny = *(const float4*)(f32 + FNY_OFF + n0);
    const float4 fnz = *(const float4*)(f32 + FNZ_OFF + n0);
    const float4 fkk = *(const float4*)(f32 + FKK_OFF + n0);
    // block-uniform scalars
    const float sx = f32[FD_OFF + ps*4u + 0];
    const float sy = f32[FD_OFF + ps*4u + 1];
    const float sz = f32[FD_OFF + ps*4u + 2];
    const float ox = f32[FPD_OFF + pp*4u + 0];
    const float oy = f32[FPD_OFF + pp*4u + 1];
    const float oz = f32[FPD_OFF + pp*4u + 2];
    const unsigned em = (q == 0u) ? emptyMask[pp] : 0u;
    const float S1u = fabsf(sx) + fabsf(sy) + fabsf(sz);
    const float O1u = fabsf(ox) + fabsf(oy) + fabsf(oz);
    const float Evd = CEPS * S1u;
    const float Eb0 = S1u + O1u;          // e1/e2 magnitude base
    const float SOu = S1u * O1u;          // vd*o magnitude base for R

    // stage W window (42 rows x 12 floats) + ray d-vectors
    if (tid < 126u) {
        unsigned row = tid / 3u, quad = tid - row*3u;
        unsigned gn = nn0 + row; if (gn > 1023u) gn = 1023u;
        const float4 v = *(const float4*)(f32 + FW_OFF + gn*12u + quad*4u);
        *(float4*)(&sW[row][quad*4u]) = v;
    }
    if (tid < 25u) {
        const float4 dr = *(const float4*)(f32 + FD_OFF + (pp*25u + tid)*4u);
        sdx[tid] = dr.x; sdy[tid] = dr.y; sdz[tid] = dr.z;
        sdm[tid] = fmaxf(fabsf(dr.x), fmaxf(fabsf(dr.y), fabsf(dr.z)));
    }
    __syncthreads();

    const float nxk[4] = {fnx.x, fnx.y, fnx.z, fnx.w};
    const float nyk[4] = {fny.x, fny.y, fny.z, fny.w};
    const float nzk[4] = {fnz.x, fnz.y, fnz.z, fnz.w};
    const float kkk[4] = {fkk.x, fkk.y, fkk.z, fkk.w};

    const unsigned rem0 = (q << 10) + n0;
    unsigned nnc = rem0 / 25u;
    unsigned ssc = rem0 - nnc*25u;

    // ---- prefetch element 0 operands ----
    float cdx = sdx[ssc], cdy = sdy[ssc], cdz = sdz[ssc], cdm = sdm[ssc];
    const float* wr0 = sW[nnc - nn0];
    float cw0 = wr0[0], cw1 = wr0[1], cw2 = wr0[2];
    float cw3 = wr0[3], cw4 = wr0[4], cw5 = wr0[5];
    float cw6 = wr0[6], cw7 = wr0[7], cw8 = wr0[8];

    float res[4];
    #pragma unroll
    for (int k = 0; k < 4; ++k) {
        // ---- issue element k+1's LDS loads FIRST (hidden under compute) ----
        unsigned ssn = ssc + 1u;
        const bool wrap = (ssn == 25u);
        unsigned nnn = nnc + (wrap ? 1u : 0u);
        ssn = wrap ? 0u : ssn;
        float ndx = 0.f, ndy = 0.f, ndz = 0.f, ndm = 0.f;
        float nw0 = 0.f, nw1 = 0.f, nw2 = 0.f, nw3 = 0.f, nw4 = 0.f;
        float nw5 = 0.f, nw6 = 0.f, nw7 = 0.f, nw8 = 0.f;
        if (k < 3) {
            ndx = sdx[ssn]; ndy = sdy[ssn]; ndz = sdz[ssn]; ndm = sdm[ssn];
            const float* wn = sW[nnn - nn0];
            nw0 = wn[0]; nw1 = wn[1]; nw2 = wn[2];
            nw3 = wn[3]; nw4 = wn[4]; nw5 = wn[5];
            nw6 = wn[6]; nw7 = wn[7]; nw8 = wn[8];
        }

        // ---- compute element k from current (c*) operands ----
        const float nx = nxk[k], ny = nyk[k], nz = nzk[k], kk = kkk[k];
        const float vd = fmaf(sz, nz, fmaf(sy, ny, sx*nx));
        const float tt = fmaf(oz, nz, fmaf(oy, ny, fmaf(ox, nx, kk)));
        const float e1 = fmaf(1e-4f, vd, -tt);     // t > -1e-4
        const float e2 = vd + tt;                  // t < 1

        const float R0 = fmaf(-tt, cdx, vd*ox);
        const float R1 = fmaf(-tt, cdy, vd*oy);
        const float R2 = fmaf(-tt, cdz, vd*oz);

        const float dG = fmaf(R2, cw2, fmaf(R1, cw1, R0*cw0));
        const float dB = fmaf(R2, cw5, fmaf(R1, cw4, R0*cw3));
        const float dA = fmaf(R2, cw8, fmaf(R1, cw7, R0*cw6));

        const int hv = __float_as_int(vd);
        int msk = (__float_as_int(e1)^hv) | (__float_as_int(e2)^hv)
                | (__float_as_int(dG)^hv) | (__float_as_int(dB)^hv)
                | (__float_as_int(dA)^hv);
        bool ok = (msk >= 0) && !((nnc < 8u) && ((em >> nnc) & 1u));

        // rounding-error guards (identical semantics to rounds 7-13)
        const float akk = fabsf(kk);
        const float Ee  = CEPS * (Eb0 + akk);
        const float Mtt = O1u + akk;
        const float MR  = fmaf(Mtt, cdm, SOu);
        const float Edx = CEPS * MR;
        const float mind = fminf(fabsf(dG), fminf(fabsf(dB), fabsf(dA)));
        const bool flag = (fabsf(vd) < Evd) | (fabsf(e1) < Ee)
                        | (fabsf(e2) < Ee) | (mind < Edx);

        float r = ok ? 1.0f : 0.0f;
        if (__builtin_expect(flag, 0)) {
            const unsigned bit = recheck64(ws, ps, pp, n0 + (unsigned)k, nnc, ssc);
            const bool okEmpty = !((nnc < 8u) && ((em >> nnc) & 1u));
            r = (bit && okEmpty) ? 1.0f : 0.0f;
        }
        res[k] = r;

        // ---- rotate prefetched operands into current (renamed by unroll) ----
        nnc = nnn; ssc = ssn;
        cdx = ndx; cdy = ndy; cdz = ndz; cdm = ndm;
        cw0 = nw0; cw1 = nw1; cw2 = nw2;
        cw3 = nw3; cw4 = nw4; cw5 = nw5;
        cw6 = nw6; cw7 = nw7; cw8 = nw8;
    }
    *(float4*)(out + (ps << 10) + n0) = make_float4(res[0], res[1], res[2], res[3]);
}

extern "C" void kernel_launch(void* const* d_in, const int* in_sizes, int n_in,
                              void* d_out, int out_size, void* d_ws, size_t ws_size,
                              hipStream_t stream) {
    const float* V         = (const float*)d_in[0];
    const int*   indices   = (const int*)  d_in[1];
    const int*   pointindex= (const int*)  d_in[2];
    const float* COL       = (const float*)d_in[3];
    const float* OPA       = (const float*)d_in[4];
    const float* p         = (const float*)d_in[5];
    const float* l         = (const float*)d_in[6];
    // d_in[7] = normals (unused), d_in[8] = it (unused)
    const float* hemi      = (const float*)d_in[9];

    float* out = (float*)d_out;
    double* ws = (double*)d_ws;
    unsigned* emptyMask = (unsigned*)((char*)d_ws + EMPTY_OFF);

    prep_all<<<55, 256, 0, stream>>>(p, l, hemi, V, indices, pointindex,
                                     COL, OPA, ws, emptyMask, out);
    diffuse_main<<<NPS, 256, 0, stream>>>(ws, emptyMask, out);
}

// Round 15
// 33.653 us; speedup vs baseline: 1.1368x; 1.1368x over previous
//
#include <hip/hip_runtime.h>
#include <math.h>

#define NP   512
#define NT   1024
#define NS   25
#define NPS  (NP*NS)            // 12800
#define MASKN (NP*NT*NS)        // 13107200

// ---- f64 region (double offsets) ----
#define DSA_OFF  0              // dsA [NPS][4]
#define PD_OFF   51200          // pd  [NP][4]
#define NX_OFF   53248
#define NY_OFF   54272
#define NZ_OFF   55296
#define KK_OFF   56320
#define W_OFF    57344          // W64 [NT][10] sign-folded
#define EMPTY_OFF ((size_t)67584 * 8)      // u32[512]
// ---- f32 shadow region (float offsets from F32 base) ----
#define F32_BYTE_OFF (EMPTY_OFF + 2048)
#define FD_OFF   0              // d32  [NPS][4]
#define FPD_OFF  51200          // pd32 [NP][4]
#define FNX_OFF  53248
#define FNY_OFF  54272
#define FNZ_OFF  55296
#define FKK_OFF  56320
#define FW_OFF   57344          // W32 [NT][12], rows prescaled to sum|w|=1

#define CEPS 7.6293945e-06f     // 64 * 2^-23

__device__ __forceinline__ double sgn(double x) {
    return (x > 0.0) ? 1.0 : ((x < 0.0) ? -1.0 : 0.0);
}

// Fused prep: blocks 0..49 rays, 50..53 triangle tables, 54 scatter+emptyMask.
__global__ void prep_all(const float* __restrict__ p,
                         const float* __restrict__ l,
                         const float* __restrict__ hemi,
                         const float* __restrict__ V,
                         const int* __restrict__ indices,
                         const int* __restrict__ pointindex,
                         const float* __restrict__ COL,
                         const float* __restrict__ OPA,
                         double* __restrict__ ws,
                         unsigned* __restrict__ emptyMask,
                         float* __restrict__ out) {
    const int b = blockIdx.x, t = threadIdx.x;
    float* __restrict__ f32w = (float*)((char*)ws + F32_BYTE_OFF);
    if (b < 50) {
        int idx = b * 256 + t;                 // < 12800 exactly
        int pi = idx / NS, si = idx % NS;
        double px = p[pi*3+0], py = p[pi*3+1], pz = p[pi*3+2];
        double lx = l[0], ly = l[1], lz = l[2];
        double ux = lx - px, uy = ly - py, uz = lz - pz;
        double nrm = sqrt(ux*ux + uy*uy + uz*uz);
        ux /= nrm; uy /= nrm; uz /= nrm;
        double c = -uy;
        double wx = -uz, wz = ux;              // w = cross((0,-1,0), u_hat), wy=0
        double m01 = -wz, m10 = wz, m12 = -wx, m21 = wx;
        double q00 = m01*m10;
        double q02 = m01*m12;
        double q11 = m10*m01 + m12*m21;
        double q20 = m21*m10;
        double q22 = m21*m12;
        double ic = 1.0 + c;
        double r00 = 1.0 + q00/ic, r01 = m01,            r02 = q02/ic;
        double r10 = m10,          r11 = 1.0 + q11/ic,   r12 = m12;
        double r20 = q20/ic,       r21 = m21,            r22 = 1.0 + q22/ic;
        double hx = hemi[si*3+0], hy = hemi[si*3+1], hz = hemi[si*3+2];
        double dx = r00*hx + r01*hy + r02*hz + lx - px;
        double dy = r10*hx + r11*hy + r12*hz + ly - py;
        double dz = r20*hx + r21*hy + r22*hz + lz - pz;
        double* dsA = ws + DSA_OFF;
        dsA[idx*4+0] = dx;
        dsA[idx*4+1] = dy;
        dsA[idx*4+2] = dz;
        dsA[idx*4+3] = 0.0;
        *(float4*)(f32w + FD_OFF + idx*4) =
            make_float4((float)dx, (float)dy, (float)dz, 0.0f);
    } else if (b < 54) {
        int n = (b - 50) * 256 + t;            // < 1024 exactly
        const float* v = V + n*12;
        double a0=v[0], a1=v[1], a2=v[2];
        double b0=v[3], b1=v[4], b2=v[5];
        double c0=v[6], c1=v[7], c2=v[8];
        double v3x=v[9], v3y=v[10], v3z=v[11];
        double e1x=b0-a0, e1y=b1-a1, e1z=b2-a2;
        double e2x=c0-a0, e2y=c1-a1, e2z=c2-a2;
        double cx = e1y*e2z - e1z*e2y;
        double cy = e1z*e2x - e1x*e2z;
        double cz = e1x*e2y - e1y*e2x;
        double nn = sqrt(cx*cx + cy*cy + cz*cz);
        double nx = cx/nn, ny = cy/nn, nz = cz/nn;
        double kk = -(nx*v3x + ny*v3y + nz*v3z);
        double Bv = a0*b2 - a2*b0;
        double Dv = a0*b1 - a1*b0;
        double Ec = a0*c2 - a2*c0;
        double G2 = a1*c0 - a0*c1;
        double Fc = Bv*G2;
        double gd = Dv*(Ec*Dv + Fc);
        double gq = Dv*gd;
        double dq = Dv*c0;
        double aq = a0*gq;
        double WGr0 = a1*Bv - a2*Dv, WGr1 = -(a0*Bv), WGr2 = a0*Dv;
        double dg = Dv*G2;
        double WBr0 = -(a1*gd) + dg*WGr0;
        double WBr1 =  a0*gd  + dg*WGr1;
        double WBr2 =            dg*WGr2;
        double dd = Dv*dq;
        double WAr0 = gq - b0*WBr0 - dd*WGr0;
        double WAr1 =    - b0*WBr1 - dd*WGr1;
        double WAr2 =    - b0*WBr2 - dd*WGr2;
        double sg = sgn(Dv*gd), sb = sgn(gq), sa = sgn(aq);
        ws[NX_OFF + n] = nx;
        ws[NY_OFF + n] = ny;
        ws[NZ_OFF + n] = nz;
        ws[KK_OFF + n] = kk;
        double g0 = WGr0*sg, g1 = WGr1*sg, g2 = WGr2*sg;
        double bb0 = WBr0*sb, bb1 = WBr1*sb, bb2 = WBr2*sb;
        double aa0 = WAr0*sa, aa1 = WAr1*sa, aa2 = WAr2*sa;
        double* W = ws + W_OFF + n*10;
        W[0]=g0; W[1]=g1; W[2]=g2;
        W[3]=bb0; W[4]=bb1; W[5]=bb2;
        W[6]=aa0; W[7]=aa1; W[8]=aa2;
        W[9]=0.0;
        // f32 shadows
        f32w[FNX_OFF+n]=(float)nx; f32w[FNY_OFF+n]=(float)ny;
        f32w[FNZ_OFF+n]=(float)nz; f32w[FKK_OFF+n]=(float)kk;
        double wsg = fabs(g0)+fabs(g1)+fabs(g2);
        double wsb = fabs(bb0)+fabs(bb1)+fabs(bb2);
        double wsa = fabs(aa0)+fabs(aa1)+fabs(aa2);
        double ig = wsg>0.0 ? 1.0/wsg : 0.0;
        double ib = wsb>0.0 ? 1.0/wsb : 0.0;
        double ia = wsa>0.0 ? 1.0/wsa : 0.0;
        float* fw = f32w + FW_OFF + n*12;
        fw[0]=(float)(g0*ig);  fw[1]=(float)(g1*ig);  fw[2]=(float)(g2*ig);
        fw[3]=(float)(bb0*ib); fw[4]=(float)(bb1*ib); fw[5]=(float)(bb2*ib);
        fw[6]=(float)(aa0*ia); fw[7]=(float)(aa1*ia); fw[8]=(float)(aa2*ia);
        fw[9]=0.0f; fw[10]=0.0f; fw[11]=0.0f;
    } else {
        emptyMask[t] = 0u;
        emptyMask[t + 256] = 0u;
        __syncthreads();
        for (int i = t; i < NP; i += 256) {
            int pidx = pointindex[i];
            int local = pidx & (NP - 1);
            int surf = indices[pidx*2 + 0];
            int mat  = indices[pidx*2 + 1];
            atomicOr(&emptyMask[local], 1u << surf);
            float* colOut = out + MASKN;
            float* opaOut = out + MASKN + 3*NP;
            float* refOut = out + MASKN + 4*NP;
            colOut[i*3+0] = COL[(surf*8+mat)*3+0];
            colOut[i*3+1] = COL[(surf*8+mat)*3+1];
            colOut[i*3+2] = COL[(surf*8+mat)*3+2];
            float o = OPA[surf*8+mat];
            opaOut[i] = fminf(fmaxf(o, 0.0f), 1.0f);
            refOut[i*3+0] = (float)((double)l[0] - (double)p[i*3+0]);
            refOut[i*3+1] = (float)((double)l[1] - (double)p[i*3+1]);
            refOut[i*3+2] = (float)((double)l[2] - (double)p[i*3+2]);
            double* pd = ws + PD_OFF;
            pd[i*4+0] = (double)p[i*3+0];
            pd[i*4+1] = (double)p[i*3+1];
            pd[i*4+2] = (double)p[i*3+2];
            pd[i*4+3] = 0.0;
            *(float4*)(f32w + FPD_OFF + i*4) =
                make_float4(p[i*3+0], p[i*3+1], p[i*3+2], 0.0f);
        }
    }
}

// Exact f64 recheck for flagged (borderline) elements — identical math to the
// validated round-4..6 f64 pipeline.
__device__ __forceinline__ float recheck64(const double* __restrict__ ws,
        unsigned ps, unsigned pp, unsigned i, unsigned nn, unsigned ss,
        unsigned em) {
    const double* s = ws + DSA_OFF + ps*4u;
    const double* o = ws + PD_OFF + pp*4u;
    double nx = ws[NX_OFF+i], ny = ws[NY_OFF+i], nz = ws[NZ_OFF+i];
    double kk = ws[KK_OFF+i];
    double vd = fma(s[2], nz, fma(s[1], ny, s[0]*nx));
    double tt = fma(o[2], nz, fma(o[1], ny, fma(o[0], nx, kk)));
    double e1 = fma(1e-4, vd, -tt);
    double e2 = vd + tt;
    const double* d = ws + DSA_OFF + (pp*25u + ss)*4u;
    double R0 = fma(-tt, d[0], vd*o[0]);
    double R1 = fma(-tt, d[1], vd*o[1]);
    double R2 = fma(-tt, d[2], vd*o[2]);
    const double* w = ws + W_OFF + nn*10u;
    double dG = fma(R2, w[2], fma(R1, w[1], R0*w[0]));
    double dB = fma(R2, w[5], fma(R1, w[4], R0*w[3]));
    double dA = fma(R2, w[8], fma(R1, w[7], R0*w[6]));
    int hv = __double2hiint(vd);
    int m = (__double2hiint(e1)^hv) | (__double2hiint(e2)^hv)
          | (__double2hiint(dG)^hv) | (__double2hiint(dB)^hv)
          | (__double2hiint(dA)^hv);
    bool ok = (m >= 0) && !((nn < 8u) && ((em >> nn) & 1u));
    return ok ? 1.0f : 0.0f;
}

// Champion kernel (round 7, best measured 33.6us): f32 fast path with
// rigorous rounding-error guards + exact f64 recheck of flagged elements.
// One block per ps-line, 4 elements/thread, lean registers, per-element
// LDS b32 reads. Empirically optimal against 7 structural variants
// (less-LDS, less-VALU, less-VMEM, more-TLP, pipelining all neutral/worse).
__global__ __launch_bounds__(256, 4) void diffuse_main(
        const double* __restrict__ ws,
        const unsigned* __restrict__ emptyMask,
        float* __restrict__ out) {
    __shared__ float sW[42][12];
    __shared__ float sdx[25], sdy[25], sdz[25], sdm[25];

    const float* __restrict__ f32 = (const float*)((const char*)ws + F32_BYTE_OFF);
    const unsigned ps = blockIdx.x;
    const unsigned pp = ps / 25u;
    const unsigned q  = ps - pp*25u;
    const unsigned nn0 = (q << 10) / 25u;
    const unsigned tid = threadIdx.x;
    const unsigned n0 = tid * 4u;

    // per-thread coalesced table loads (f32)
    const float4 fnx = *(const float4*)(f32 + FNX_OFF + n0);
    const float4 fny = *(const float4*)(f32 + FNY_OFF + n0);
    const float4 fnz = *(const float4*)(f32 + FNZ_OFF + n0);
    const float4 fkk = *(const float4*)(f32 + FKK_OFF + n0);
    // block-uniform scalars
    const float sx = f32[FD_OFF + ps*4u + 0];
    const float sy = f32[FD_OFF + ps*4u + 1];
    const float sz = f32[FD_OFF + ps*4u + 2];
    const float ox = f32[FPD_OFF + pp*4u + 0];
    const float oy = f32[FPD_OFF + pp*4u + 1];
    const float oz = f32[FPD_OFF + pp*4u + 2];
    const unsigned em = (q == 0u) ? emptyMask[pp] : 0u;
    const float S1u = fabsf(sx) + fabsf(sy) + fabsf(sz);
    const float O1u = fabsf(ox) + fabsf(oy) + fabsf(oz);
    const float Evd = CEPS * S1u;
    const float Eb0 = S1u + O1u;          // e1/e2 magnitude base
    const float SOu = S1u * O1u;          // vd*o magnitude base for R

    // stage W window (42 rows x 12 floats) + ray d-vectors
    if (tid < 126u) {
        unsigned row = tid / 3u, quad = tid - row*3u;
        unsigned gn = nn0 + row; if (gn > 1023u) gn = 1023u;
        const float4 v = *(const float4*)(f32 + FW_OFF + gn*12u + quad*4u);
        *(float4*)(&sW[row][quad*4u]) = v;
    }
    if (tid < 25u) {
        const float4 dr = *(const float4*)(f32 + FD_OFF + (pp*25u + tid)*4u);
        sdx[tid] = dr.x; sdy[tid] = dr.y; sdz[tid] = dr.z;
        sdm[tid] = fmaxf(fabsf(dr.x), fmaxf(fabsf(dr.y), fabsf(dr.z)));
    }
    __syncthreads();

    const float nxk[4] = {fnx.x, fnx.y, fnx.z, fnx.w};
    const float nyk[4] = {fny.x, fny.y, fny.z, fny.w};
    const float nzk[4] = {fnz.x, fnz.y, fnz.z, fnz.w};
    const float kkk[4] = {fkk.x, fkk.y, fkk.z, fkk.w};

    unsigned rem = (q << 10) + n0;
    unsigned nn = rem / 25u;
    unsigned ss = rem - nn*25u;

    float res[4];
    #pragma unroll
    for (int k = 0; k < 4; ++k) {
        const float nx = nxk[k], ny = nyk[k], nz = nzk[k], kk = kkk[k];
        const float vd = fmaf(sz, nz, fmaf(sy, ny, sx*nx));
        const float tt = fmaf(oz, nz, fmaf(oy, ny, fmaf(ox, nx, kk)));
        const float e1 = fmaf(1e-4f, vd, -tt);     // t > -1e-4
        const float e2 = vd + tt;                  // t < 1

        const float dxv = sdx[ss], dyv = sdy[ss], dzv = sdz[ss], dmv = sdm[ss];
        const float R0 = fmaf(-tt, dxv, vd*ox);
        const float R1 = fmaf(-tt, dyv, vd*oy);
        const float R2 = fmaf(-tt, dzv, vd*oz);

        const float* w = sW[nn - nn0];
        const float dG = fmaf(R2, w[2], fmaf(R1, w[1], R0*w[0]));
        const float dB = fmaf(R2, w[5], fmaf(R1, w[4], R0*w[3]));
        const float dA = fmaf(R2, w[8], fmaf(R1, w[7], R0*w[6]));

        const int hv = __float_as_int(vd);
        int msk = (__float_as_int(e1)^hv) | (__float_as_int(e2)^hv)
                | (__float_as_int(dG)^hv) | (__float_as_int(dB)^hv)
                | (__float_as_int(dA)^hv);
        bool ok = (msk >= 0) && !((nn < 8u) && ((em >> nn) & 1u));

        // --- rounding-error guards (magnitude-based, cancellation-safe) ---
        const float akk = fabsf(kk);
        const float Ee  = CEPS * (Eb0 + akk);               // e1,e2 bound
        const float Mtt = O1u + akk;                        // >= |tt| and err scale
        const float MR  = fmaf(Mtt, dmv, SOu);              // >= |R_i| and err scale
        const float Edx = CEPS * MR;                        // dG/dB/dA bound (sum|w|=1)
        const float mind = fminf(fabsf(dG), fminf(fabsf(dB), fabsf(dA)));
        const bool flag = (fabsf(vd) < Evd) | (fabsf(e1) < Ee)
                        | (fabsf(e2) < Ee) | (mind < Edx);

        float r = ok ? 1.0f : 0.0f;
        if (__builtin_expect(flag, 0))
            r = recheck64(ws, ps, pp, n0 + (unsigned)k, nn, ss, em);
        res[k] = r;

        ss += 1u;
        const bool wrap = (ss == 25u);
        nn += wrap ? 1u : 0u;
        ss  = wrap ? 0u : ss;
    }
    *(float4*)(out + (ps << 10) + n0) = make_float4(res[0], res[1], res[2], res[3]);
}

extern "C" void kernel_launch(void* const* d_in, const int* in_sizes, int n_in,
                              void* d_out, int out_size, void* d_ws, size_t ws_size,
                              hipStream_t stream) {
    const float* V         = (const float*)d_in[0];
    const int*   indices   = (const int*)  d_in[1];
    const int*   pointindex= (const int*)  d_in[2];
    const float* COL       = (const float*)d_in[3];
    const float* OPA       = (const float*)d_in[4];
    const float* p         = (const float*)d_in[5];
    const float* l         = (const float*)d_in[6];
    // d_in[7] = normals (unused), d_in[8] = it (unused)
    const float* hemi      = (const float*)d_in[9];

    float* out = (float*)d_out;
    double* ws = (double*)d_ws;
    unsigned* emptyMask = (unsigned*)((char*)d_ws + EMPTY_OFF);

    prep_all<<<55, 256, 0, stream>>>(p, l, hemi, V, indices, pointindex,
                                     COL, OPA, ws, emptyMask, out);
    diffuse_main<<<NPS, 256, 0, stream>>>(ws, emptyMask, out);
}